// Round 1
// baseline (1230.215 us; speedup 1.0000x reference)
//
#include <hip/hip_runtime.h>

// Problem constants (B,C,H,W) = (8,512,64,64)
constexpr int BATCH = 8;
constexpr int C = 512;
constexpr int HW = 4096;                 // n = h*w
constexpr long CN = (long)C * HW;        // per-batch x / y elements
constexpr long CC = (long)C * C;         // per-batch 512x512 matrices

#define TILE 64
#define BK 16

// ---------------------------------------------------------------------------
// GEMM NT: C[M,N] = A[M,K] * B[N,K]^T   (A,B row-major, K is the fast dim)
// Used for: Gram = X X^T (M=N=512,K=4096), logits = T1 * w_theta^T
// ---------------------------------------------------------------------------
__global__ __launch_bounds__(256) void gemm_nt_k(
    const float* __restrict__ A, const float* __restrict__ B,
    float* __restrict__ Cmat, int M, int N, int K,
    long aB, long bB, long cB) {
  const int bz = blockIdx.z;
  const float* Ab = A + (long)bz * aB;
  const float* Bb = B + (long)bz * bB;
  float* Cb = Cmat + (long)bz * cB;

  __shared__ float As[BK][TILE + 1];   // [k][m], +1 pad: transpose-on-store
  __shared__ float Bs[BK][TILE + 1];   // [k][n]

  const int tx = threadIdx.x, ty = threadIdx.y;   // 16x16
  const int tid = ty * 16 + tx;
  const int row0 = blockIdx.y * TILE;
  const int col0 = blockIdx.x * TILE;

  float acc[4][4] = {};

  for (int k0 = 0; k0 < K; k0 += BK) {
    // 64 rows x 16 k per tile = 1024 elems; 256 threads -> 4 each. Coalesced
    // along k (fast dim), transposed into LDS.
#pragma unroll
    for (int i = 0; i < 4; ++i) {
      int e = tid + i * 256;
      int r = e >> 4, c = e & 15;
      As[c][r] = Ab[(long)(row0 + r) * K + k0 + c];
      Bs[c][r] = Bb[(long)(col0 + r) * K + k0 + c];
    }
    __syncthreads();
#pragma unroll
    for (int k = 0; k < BK; ++k) {
      float av[4], bv[4];
#pragma unroll
      for (int i = 0; i < 4; ++i) av[i] = As[k][ty * 4 + i];
#pragma unroll
      for (int j = 0; j < 4; ++j) bv[j] = Bs[k][tx * 4 + j];
#pragma unroll
      for (int i = 0; i < 4; ++i)
#pragma unroll
        for (int j = 0; j < 4; ++j)
          acc[i][j] = fmaf(av[i], bv[j], acc[i][j]);
    }
    __syncthreads();
  }

#pragma unroll
  for (int i = 0; i < 4; ++i)
#pragma unroll
    for (int j = 0; j < 4; ++j)
      Cb[(long)(row0 + ty * 4 + i) * N + col0 + tx * 4 + j] = acc[i][j];
}

// ---------------------------------------------------------------------------
// GEMM NN: C[M,N] = A[M,K] * B[K,N]   (row-major)
// EPI 0: plain row-major store
// EPI 1: permuted store for y: element (m=c, n) -> Cb[n*M + m]
//        (this IS the torch permute(0,2,1).view(b,c,h,w): flat = n*512 + c)
// EPI 2: out = gamma * acc + x   (x read at the same row-major index)
// ---------------------------------------------------------------------------
template <int EPI>
__global__ __launch_bounds__(256) void gemm_nn_k(
    const float* __restrict__ A, const float* __restrict__ B,
    float* __restrict__ Cmat, int M, int N, int K,
    long aB, long bB, long cB,
    const float* __restrict__ X, const float* __restrict__ gammaPtr) {
  const int bz = blockIdx.z;
  const float* Ab = A + (long)bz * aB;
  const float* Bb = B + (long)bz * bB;
  float* Cb = Cmat + (long)bz * cB;

  __shared__ float As[BK][TILE + 1];   // [k][m] transposed on store (padded)
  __shared__ float Bs[BK][TILE];       // [k][n] direct (b128-friendly reads)

  const int tx = threadIdx.x, ty = threadIdx.y;
  const int tid = ty * 16 + tx;
  const int row0 = blockIdx.y * TILE;
  const int col0 = blockIdx.x * TILE;

  float acc[4][4] = {};

  for (int k0 = 0; k0 < K; k0 += BK) {
#pragma unroll
    for (int i = 0; i < 4; ++i) {
      int e = tid + i * 256;
      { // A tile: 64 rows(m) x 16 (k), coalesced along k, transposed store
        int r = e >> 4, c = e & 15;
        As[c][r] = Ab[(long)(row0 + r) * K + k0 + c];
      }
      { // B tile: 16 rows(k) x 64 (n), coalesced along n, direct store
        int r = e >> 6, c = e & 63;
        Bs[r][c] = Bb[(long)(k0 + r) * N + col0 + c];
      }
    }
    __syncthreads();
#pragma unroll
    for (int k = 0; k < BK; ++k) {
      float av[4], bv[4];
#pragma unroll
      for (int i = 0; i < 4; ++i) av[i] = As[k][ty * 4 + i];
#pragma unroll
      for (int j = 0; j < 4; ++j) bv[j] = Bs[k][tx * 4 + j];
#pragma unroll
      for (int i = 0; i < 4; ++i)
#pragma unroll
        for (int j = 0; j < 4; ++j)
          acc[i][j] = fmaf(av[i], bv[j], acc[i][j]);
    }
    __syncthreads();
  }

  if (EPI == 0) {
#pragma unroll
    for (int i = 0; i < 4; ++i)
#pragma unroll
      for (int j = 0; j < 4; ++j)
        Cb[(long)(row0 + ty * 4 + i) * N + col0 + tx * 4 + j] = acc[i][j];
  } else if (EPI == 1) {
#pragma unroll
    for (int i = 0; i < 4; ++i)
#pragma unroll
      for (int j = 0; j < 4; ++j) {
        int m = row0 + ty * 4 + i;
        int n = col0 + tx * 4 + j;
        Cb[(long)n * M + m] = acc[i][j];
      }
  } else {
    const float g0 = gammaPtr[0];
    const float* Xb = X + (long)bz * cB;
#pragma unroll
    for (int i = 0; i < 4; ++i)
#pragma unroll
      for (int j = 0; j < 4; ++j) {
        long idx = (long)(row0 + ty * 4 + i) * N + col0 + tx * 4 + j;
        Cb[idx] = g0 * acc[i][j] + Xb[idx];
      }
  }
}

// ---------------------------------------------------------------------------
// Row softmax over 512 columns; one 256-thread block per row; in place.
// ---------------------------------------------------------------------------
__global__ __launch_bounds__(256) void softmax_k(float* __restrict__ a) {
  float* row = a + (long)blockIdx.x * 512;
  const int t = threadIdx.x;
  float v0 = row[t], v1 = row[t + 256];
  __shared__ float sm[256];
  sm[t] = fmaxf(v0, v1);
  __syncthreads();
  for (int s = 128; s > 0; s >>= 1) {
    if (t < s) sm[t] = fmaxf(sm[t], sm[t + s]);
    __syncthreads();
  }
  float mx = sm[0];
  __syncthreads();
  float e0 = expf(v0 - mx), e1 = expf(v1 - mx);
  sm[t] = e0 + e1;
  __syncthreads();
  for (int s = 128; s > 0; s >>= 1) {
    if (t < s) sm[t] += sm[t + s];
    __syncthreads();
  }
  float inv = 1.0f / sm[0];
  row[t] = e0 * inv;
  row[t + 256] = e1 * inv;
}

// ---------------------------------------------------------------------------
// Orchestration.
//   gram   = X X^T                      (per batch, 512x512, K=4096)
//   t1     = w_phi  @ gram
//   logits = t1 @ w_theta^T             (== w_phi Gram w_theta^T == phi theta^T)
//   attn   = softmax_rows(logits)
//   Mb     = attn @ w_g                 (fold attn into the 1x1-conv weight)
//   y      = Mb @ X      -> stored permuted (flat n*512+c) == torch view trick
//   out    = gamma * (w_mask @ y_view) + x
// Workspace: bufA(2M) + bufB(2M) + yv(16.7M) floats = 83.9 MB.
// ---------------------------------------------------------------------------
extern "C" void kernel_launch(void* const* d_in, const int* in_sizes, int n_in,
                              void* d_out, int out_size, void* d_ws, size_t ws_size,
                              hipStream_t stream) {
  const float* x       = (const float*)d_in[0];
  const float* w_phi   = (const float*)d_in[1];
  const float* w_theta = (const float*)d_in[2];
  const float* w_g     = (const float*)d_in[3];
  const float* w_mask  = (const float*)d_in[4];
  const float* gamma   = (const float*)d_in[5];
  float* out = (float*)d_out;

  float* bufA = (float*)d_ws;              // 512*512*8 floats (gram -> logits/attn)
  float* bufB = bufA + CC * BATCH;         // 512*512*8 floats (t1 -> Mb)
  float* yv   = bufB + CC * BATCH;         // 512*4096*8 floats (permuted y)

  dim3 blk(16, 16);
  dim3 gridSmall(C / TILE, C / TILE, BATCH);   // 8x8x8
  dim3 gridBig(HW / TILE, C / TILE, BATCH);    // 64x8x8

  // 1. Gram[b] = X_b X_b^T
  gemm_nt_k<<<gridSmall, blk, 0, stream>>>(x, x, bufA, C, C, HW, CN, CN, CC);
  // 2. t1[b] = w_phi @ Gram[b]
  gemm_nn_k<0><<<gridSmall, blk, 0, stream>>>(w_phi, bufA, bufB, C, C, C,
                                              0, CC, CC, nullptr, nullptr);
  // 3. logits[b] = t1[b] @ w_theta^T   (-> bufA, gram dead)
  gemm_nt_k<<<gridSmall, blk, 0, stream>>>(bufB, w_theta, bufA, C, C, C, CC, 0, CC);
  // 4. attn = row-softmax(logits), in place
  softmax_k<<<dim3(BATCH * C), dim3(256), 0, stream>>>(bufA);
  // 5. Mb = attn @ w_g   (-> bufB, t1 dead)
  gemm_nn_k<0><<<gridSmall, blk, 0, stream>>>(bufA, w_g, bufB, C, C, C,
                                              CC, 0, CC, nullptr, nullptr);
  // 6. y = Mb @ X_b, stored permuted (flat n*512+c) -> yv
  gemm_nn_k<1><<<gridBig, blk, 0, stream>>>(bufB, x, yv, C, HW, C,
                                            CC, CN, CN, nullptr, nullptr);
  // 7. out = gamma * (w_mask @ yv) + x
  gemm_nn_k<2><<<gridBig, blk, 0, stream>>>(w_mask, yv, out, C, HW, C,
                                            0, CN, CN, x, gamma);
}

// Round 2
// 452.308 us; speedup vs baseline: 2.7199x; 2.7199x over previous
//
#include <hip/hip_runtime.h>
#include <hip/hip_bf16.h>

// (B,C,H,W) = (8,512,64,64)
constexpr int BATCH = 8;
constexpr int C = 512;
constexpr int HW = 4096;
constexpr long CN = (long)C * HW;   // 2,097,152
constexpr long CC = (long)C * C;    // 262,144

typedef __attribute__((ext_vector_type(8))) short short8;
typedef __attribute__((ext_vector_type(4))) float f32x4;

__device__ __forceinline__ void gload16(const void* g, void* l) {
  __builtin_amdgcn_global_load_lds(
      (const __attribute__((address_space(1))) void*)g,
      (__attribute__((address_space(3))) void*)l, 16, 0, 0);
}

// ---------------------------------------------------------------------------
// convx: X fp32 [C,HW] -> Xhi,Xlo bf16 [C,HW] (hi/lo split for Gram)
//                         Xt bf16 [HW,C]      (transpose, for the y-GEMM)
// ---------------------------------------------------------------------------
__global__ __launch_bounds__(256) void convx_k(
    const float* __restrict__ x, __hip_bfloat16* __restrict__ xhi,
    __hip_bfloat16* __restrict__ xlo, __hip_bfloat16* __restrict__ xt) {
  const int b = blockIdx.z;
  const int n0 = blockIdx.x * 64, c0 = blockIdx.y * 64;
  const float* xb = x + (long)b * CN;
  __shared__ __hip_bfloat16 t[64][65];
  const int tid = threadIdx.x;
#pragma unroll
  for (int i = 0; i < 16; ++i) {
    int e = i * 256 + tid;
    int r = e >> 6, col = e & 63;          // r: c-row, col: n
    float v = xb[(long)(c0 + r) * HW + n0 + col];
    __hip_bfloat16 h = __float2bfloat16(v);
    float lo = v - __bfloat162float(h);
    long idx = (long)b * CN + (long)(c0 + r) * HW + n0 + col;
    xhi[idx] = h;
    xlo[idx] = __float2bfloat16(lo);
    t[r][col] = h;
  }
  __syncthreads();
#pragma unroll
  for (int i = 0; i < 16; ++i) {
    int e = i * 256 + tid;
    int r = e >> 6, col = e & 63;          // r: n-row of Xt, col: c
    xt[(long)b * CN + (long)(n0 + r) * C + c0 + col] = t[col][r];
  }
}

__global__ __launch_bounds__(256) void convw_k(const float* __restrict__ w,
                                               __hip_bfloat16* __restrict__ wb) {
  int i = blockIdx.x * 1024 + threadIdx.x;
#pragma unroll
  for (int j = 0; j < 4; ++j) wb[i + j * 256] = __float2bfloat16(w[i + j * 256]);
}

// ---------------------------------------------------------------------------
// Gram = X X^T via MFMA, hi/lo split: hi*hi + hi*lo + lo*hi (fp32-grade).
// 64x64 tile/block, BK=64, grid (8,8,8)=512 blocks. LDS rows 128B, XOR swizzle
// chunkpos = c ^ (r&7) -> 2-way reads (free).
// ---------------------------------------------------------------------------
__global__ __launch_bounds__(256) void gram_k(
    const __hip_bfloat16* __restrict__ xhi, const __hip_bfloat16* __restrict__ xlo,
    float* __restrict__ gram) {
  const int b = blockIdx.z;
  const int m0 = blockIdx.y * 64, n0 = blockIdx.x * 64;
  const short* Xh = (const short*)(xhi + (long)b * CN);
  const short* Xl = (const short*)(xlo + (long)b * CN);
  __shared__ short lds[4 * 64 * 64];   // tiles: 0=Ahi 1=Alo 2=Bhi 3=Blo
  const int tid = threadIdx.x;
  const int w = tid >> 6, lane = tid & 63;

  const short* src = (w & 1) ? Xl : Xh;
  const int rowbase = (w & 2) ? n0 : m0;
  short* ltile = lds + w * 4096;

  f32x4 acc[2][2] = {};
  const int wr = (w >> 1) * 32, wc = (w & 1) * 32;

  for (int k0 = 0; k0 < HW; k0 += 64) {
#pragma unroll
    for (int i = 0; i < 8; ++i) {
      int slot = i * 64 + lane;
      int r = slot >> 3, p = slot & 7, c = p ^ (r & 7);
      gload16(src + (long)(rowbase + r) * HW + k0 + c * 8, ltile + slot * 8);
    }
    __syncthreads();
#pragma unroll
    for (int kh = 0; kh < 2; ++kh) {
      short8 ah[2], al[2], bh[2], bl[2];
      const int ch = kh * 4 + (lane >> 4);
#pragma unroll
      for (int mi = 0; mi < 2; ++mi) {
        int r = wr + mi * 16 + (lane & 15);
        int off = (r * 8 + (ch ^ (r & 7))) * 8;
        ah[mi] = *(const short8*)(lds + off);
        al[mi] = *(const short8*)(lds + 4096 + off);
      }
#pragma unroll
      for (int ni = 0; ni < 2; ++ni) {
        int r = wc + ni * 16 + (lane & 15);
        int off = (r * 8 + (ch ^ (r & 7))) * 8;
        bh[ni] = *(const short8*)(lds + 2 * 4096 + off);
        bl[ni] = *(const short8*)(lds + 3 * 4096 + off);
      }
#pragma unroll
      for (int mi = 0; mi < 2; ++mi)
#pragma unroll
        for (int ni = 0; ni < 2; ++ni) {
          acc[mi][ni] = __builtin_amdgcn_mfma_f32_16x16x32_bf16(ah[mi], bh[ni], acc[mi][ni], 0, 0, 0);
          acc[mi][ni] = __builtin_amdgcn_mfma_f32_16x16x32_bf16(ah[mi], bl[ni], acc[mi][ni], 0, 0, 0);
          acc[mi][ni] = __builtin_amdgcn_mfma_f32_16x16x32_bf16(al[mi], bh[ni], acc[mi][ni], 0, 0, 0);
        }
    }
    __syncthreads();
  }
  float* Gb = gram + (long)b * CC;
#pragma unroll
  for (int mi = 0; mi < 2; ++mi)
#pragma unroll
    for (int ni = 0; ni < 2; ++ni)
#pragma unroll
      for (int r = 0; r < 4; ++r) {
        int row = m0 + wr + mi * 16 + (lane >> 4) * 4 + r;
        int col = n0 + wc + ni * 16 + (lane & 15);
        Gb[(long)row * C + col] = acc[mi][ni][r];
      }
}

// ---------------------------------------------------------------------------
// Big NT MFMA GEMM, 128x128 tile, BK=32, M=512 N=4096 K=512.
// MODE 0: y = Mb @ X  == Mb(NT)Xt. B-rows permuted (n = n0 + u*8 + t) so the
//         permute(0,2,1).view store yvT[n'=t*512+c][c'=n0/8+u] is lane-contig.
// MODE 1: out = gamma*(w_mask(NT)yvT) + x, plain fp32 store.
// LDS rows 64B, swizzle chunkpos = c ^ ((r>>1)&3) -> 2-way reads (free).
// ---------------------------------------------------------------------------
template <int MODE>
__global__ __launch_bounds__(256) void big_k(
    const __hip_bfloat16* __restrict__ Aw, const __hip_bfloat16* __restrict__ Bm,
    void* __restrict__ Cout, const float* __restrict__ x,
    const float* __restrict__ gammaPtr, long aStride) {
  const int b = blockIdx.z;
  const int n0 = blockIdx.x * 128, m0 = blockIdx.y * 128;
  const short* A = (const short*)(Aw + (long)b * aStride);
  const short* B = (const short*)(Bm + (long)b * CN);
  __shared__ short lds[2 * 128 * 32];
  const int tid = threadIdx.x, w = tid >> 6, lane = tid & 63;

  f32x4 acc[4][4] = {};
  const int wr = (w >> 1) * 64, wc = (w & 1) * 64;

  for (int k0 = 0; k0 < 512; k0 += 32) {
    // waves 0,1 stage A (512 slots), waves 2,3 stage B
#pragma unroll
    for (int i = 0; i < 4; ++i) {
      int slot = (w & 1) * 256 + i * 64 + lane;
      int r = slot >> 2, p = slot & 3, c = p ^ ((r >> 1) & 3);
      const short* src;
      long goff;
      if (w < 2) {
        src = A;
        goff = (long)(m0 + r) * 512 + k0 + c * 8;
      } else {
        int gr = (MODE == 0) ? (n0 + (r & 15) * 8 + (r >> 4)) : (n0 + r);
        src = B;
        goff = (long)gr * 512 + k0 + c * 8;
      }
      gload16(src + goff, lds + ((w >> 1) * 512 + slot) * 8);
    }
    __syncthreads();
    short8 af[4], bfr[4];
    const int ch = lane >> 4;
#pragma unroll
    for (int mi = 0; mi < 4; ++mi) {
      int r = wr + mi * 16 + (lane & 15);
      af[mi] = *(const short8*)(lds + (r * 4 + (ch ^ ((r >> 1) & 3))) * 8);
    }
#pragma unroll
    for (int ni = 0; ni < 4; ++ni) {
      int r = wc + ni * 16 + (lane & 15);
      bfr[ni] = *(const short8*)(lds + 4096 + (r * 4 + (ch ^ ((r >> 1) & 3))) * 8);
    }
#pragma unroll
    for (int mi = 0; mi < 4; ++mi)
#pragma unroll
      for (int ni = 0; ni < 4; ++ni)
        acc[mi][ni] = __builtin_amdgcn_mfma_f32_16x16x32_bf16(af[mi], bfr[ni], acc[mi][ni], 0, 0, 0);
    __syncthreads();
  }

  if (MODE == 0) {
    __hip_bfloat16* yv = (__hip_bfloat16*)Cout + (long)b * CN;
    const int u = lane & 15;
#pragma unroll
    for (int mi = 0; mi < 4; ++mi)
#pragma unroll
      for (int ni = 0; ni < 4; ++ni) {
        int t = (wc >> 4) + ni;
        long base = ((long)(t * 512 + m0 + wr + mi * 16 + (lane >> 4) * 4)) * 512 +
                    (n0 >> 3) + u;
#pragma unroll
        for (int r = 0; r < 4; ++r)
          yv[base + (long)r * 512] = __float2bfloat16(acc[mi][ni][r]);
      }
  } else {
    float* outp = (float*)Cout + (long)b * CN;
    const float* xb = x + (long)b * CN;
    const float g0 = gammaPtr[0];
#pragma unroll
    for (int mi = 0; mi < 4; ++mi)
#pragma unroll
      for (int ni = 0; ni < 4; ++ni)
#pragma unroll
        for (int r = 0; r < 4; ++r) {
          long idx = (long)(m0 + wr + mi * 16 + (lane >> 4) * 4 + r) * HW +
                     n0 + wc + ni * 16 + (lane & 15);
          outp[idx] = g0 * acc[mi][ni][r] + xb[idx];
        }
  }
}

// ---------------------------------------------------------------------------
// Small fp32 chain (unchanged from round 1): NT, NN (+ bf16-store variant),
// softmax. ~2 GF total.
// ---------------------------------------------------------------------------
#define TILE 64
#define BK 16

__global__ __launch_bounds__(256) void gemm_nt_k(
    const float* __restrict__ A, const float* __restrict__ B,
    float* __restrict__ Cmat, int M, int N, int K, long aB, long bB, long cB) {
  const int bz = blockIdx.z;
  const float* Ab = A + (long)bz * aB;
  const float* Bb = B + (long)bz * bB;
  float* Cb = Cmat + (long)bz * cB;
  __shared__ float As[BK][TILE + 1];
  __shared__ float Bs[BK][TILE + 1];
  const int tx = threadIdx.x, ty = threadIdx.y;
  const int tid = ty * 16 + tx;
  const int row0 = blockIdx.y * TILE, col0 = blockIdx.x * TILE;
  float acc[4][4] = {};
  for (int k0 = 0; k0 < K; k0 += BK) {
#pragma unroll
    for (int i = 0; i < 4; ++i) {
      int e = tid + i * 256;
      int r = e >> 4, c = e & 15;
      As[c][r] = Ab[(long)(row0 + r) * K + k0 + c];
      Bs[c][r] = Bb[(long)(col0 + r) * K + k0 + c];
    }
    __syncthreads();
#pragma unroll
    for (int k = 0; k < BK; ++k) {
      float av[4], bv[4];
#pragma unroll
      for (int i = 0; i < 4; ++i) av[i] = As[k][ty * 4 + i];
#pragma unroll
      for (int j = 0; j < 4; ++j) bv[j] = Bs[k][tx * 4 + j];
#pragma unroll
      for (int i = 0; i < 4; ++i)
#pragma unroll
        for (int j = 0; j < 4; ++j) acc[i][j] = fmaf(av[i], bv[j], acc[i][j]);
    }
    __syncthreads();
  }
#pragma unroll
  for (int i = 0; i < 4; ++i)
#pragma unroll
    for (int j = 0; j < 4; ++j)
      Cb[(long)(row0 + ty * 4 + i) * N + col0 + tx * 4 + j] = acc[i][j];
}

// EPI 0: fp32 store; EPI 3: bf16 store
template <int EPI>
__global__ __launch_bounds__(256) void gemm_nn_k(
    const float* __restrict__ A, const float* __restrict__ B,
    float* __restrict__ Cmat, int M, int N, int K, long aB, long bB, long cB) {
  const int bz = blockIdx.z;
  const float* Ab = A + (long)bz * aB;
  const float* Bb = B + (long)bz * bB;
  __shared__ float As[BK][TILE + 1];
  __shared__ float Bs[BK][TILE];
  const int tx = threadIdx.x, ty = threadIdx.y;
  const int tid = ty * 16 + tx;
  const int row0 = blockIdx.y * TILE, col0 = blockIdx.x * TILE;
  float acc[4][4] = {};
  for (int k0 = 0; k0 < K; k0 += BK) {
#pragma unroll
    for (int i = 0; i < 4; ++i) {
      int e = tid + i * 256;
      {
        int r = e >> 4, c = e & 15;
        As[c][r] = Ab[(long)(row0 + r) * K + k0 + c];
      }
      {
        int r = e >> 6, c = e & 63;
        Bs[r][c] = Bb[(long)(k0 + r) * N + col0 + c];
      }
    }
    __syncthreads();
#pragma unroll
    for (int k = 0; k < BK; ++k) {
      float av[4], bv[4];
#pragma unroll
      for (int i = 0; i < 4; ++i) av[i] = As[k][ty * 4 + i];
#pragma unroll
      for (int j = 0; j < 4; ++j) bv[j] = Bs[k][tx * 4 + j];
#pragma unroll
      for (int i = 0; i < 4; ++i)
#pragma unroll
        for (int j = 0; j < 4; ++j) acc[i][j] = fmaf(av[i], bv[j], acc[i][j]);
    }
    __syncthreads();
  }
  if (EPI == 0) {
    float* Cb = Cmat + (long)bz * cB;
#pragma unroll
    for (int i = 0; i < 4; ++i)
#pragma unroll
      for (int j = 0; j < 4; ++j)
        Cb[(long)(row0 + ty * 4 + i) * N + col0 + tx * 4 + j] = acc[i][j];
  } else {
    __hip_bfloat16* Cb = (__hip_bfloat16*)Cmat + (long)bz * cB;
#pragma unroll
    for (int i = 0; i < 4; ++i)
#pragma unroll
      for (int j = 0; j < 4; ++j)
        Cb[(long)(row0 + ty * 4 + i) * N + col0 + tx * 4 + j] =
            __float2bfloat16(acc[i][j]);
  }
}

__global__ __launch_bounds__(256) void softmax_k(float* __restrict__ a) {
  float* row = a + (long)blockIdx.x * 512;
  const int t = threadIdx.x;
  float v0 = row[t], v1 = row[t + 256];
  __shared__ float sm[256];
  sm[t] = fmaxf(v0, v1);
  __syncthreads();
  for (int s = 128; s > 0; s >>= 1) {
    if (t < s) sm[t] = fmaxf(sm[t], sm[t + s]);
    __syncthreads();
  }
  float mx = sm[0];
  __syncthreads();
  float e0 = expf(v0 - mx), e1 = expf(v1 - mx);
  sm[t] = e0 + e1;
  __syncthreads();
  for (int s = 128; s > 0; s >>= 1) {
    if (t < s) sm[t] += sm[t + s];
    __syncthreads();
  }
  float inv = 1.0f / sm[0];
  row[t] = e0 * inv;
  row[t + 256] = e1 * inv;
}

// ---------------------------------------------------------------------------
// Orchestration. Workspace ~156 MB:
//   xhi/xlo/xt/yvT: 4 x 33.6 MB bf16; mb16 4.2 MB; wm16 0.5 MB;
//   bufA/bufB: 2 x 8.4 MB fp32.
// ---------------------------------------------------------------------------
extern "C" void kernel_launch(void* const* d_in, const int* in_sizes, int n_in,
                              void* d_out, int out_size, void* d_ws, size_t ws_size,
                              hipStream_t stream) {
  const float* x       = (const float*)d_in[0];
  const float* w_phi   = (const float*)d_in[1];
  const float* w_theta = (const float*)d_in[2];
  const float* w_g     = (const float*)d_in[3];
  const float* w_mask  = (const float*)d_in[4];
  const float* gamma   = (const float*)d_in[5];
  float* out = (float*)d_out;

  __hip_bfloat16* xhi  = (__hip_bfloat16*)d_ws;
  __hip_bfloat16* xlo  = xhi + BATCH * CN;
  __hip_bfloat16* xt   = xlo + BATCH * CN;
  __hip_bfloat16* yvT  = xt + BATCH * CN;
  __hip_bfloat16* mb16 = yvT + BATCH * CN;
  __hip_bfloat16* wm16 = mb16 + BATCH * CC;
  float* bufA = (float*)(wm16 + CC);
  float* bufB = bufA + BATCH * CC;

  dim3 blk16(16, 16);
  dim3 gridSmall(8, 8, BATCH);

  // 0. conversions: hi/lo split + transpose; w_mask -> bf16
  convx_k<<<dim3(64, 8, BATCH), 256, 0, stream>>>(x, xhi, xlo, xt);
  convw_k<<<dim3(256), 256, 0, stream>>>(w_mask, wm16);
  // 1. Gram = X X^T  (MFMA, hi/lo)
  gram_k<<<dim3(8, 8, BATCH), 256, 0, stream>>>(xhi, xlo, bufA);
  // 2. t1 = w_phi @ Gram
  gemm_nn_k<0><<<gridSmall, blk16, 0, stream>>>(w_phi, bufA, bufB, C, C, C, 0, CC, CC);
  // 3. logits = t1 @ w_theta^T
  gemm_nt_k<<<gridSmall, blk16, 0, stream>>>(bufB, w_theta, bufA, C, C, C, CC, 0, CC);
  // 4. attn = row-softmax(logits)
  softmax_k<<<dim3(BATCH * C), dim3(256), 0, stream>>>(bufA);
  // 5. Mb = bf16(attn @ w_g)
  gemm_nn_k<3><<<gridSmall, blk16, 0, stream>>>(bufA, w_g, (float*)mb16, C, C, C, CC, 0, CC);
  // 6. y = Mb (NT) Xt -> yvT (permuted bf16 store == torch permute+view, pre-transposed)
  big_k<0><<<dim3(32, 4, BATCH), 256, 0, stream>>>(mb16, xt, yvT, nullptr, nullptr, CC);
  // 7. out = gamma * (w_mask (NT) yvT) + x
  big_k<1><<<dim3(32, 4, BATCH), 256, 0, stream>>>(wm16, yvT, out, x, gamma, 0);
}

// Round 3
// 329.025 us; speedup vs baseline: 3.7390x; 1.3747x over previous
//
#include <hip/hip_runtime.h>
#include <hip/hip_bf16.h>

// (B,C,H,W) = (8,512,64,64)
constexpr int BATCH = 8;
constexpr int C = 512;
constexpr int HW = 4096;
constexpr long CN = (long)C * HW;   // 2,097,152
constexpr long CC = (long)C * C;    // 262,144

typedef __attribute__((ext_vector_type(8))) short short8;
typedef __attribute__((ext_vector_type(4))) float f32x4;

__device__ __forceinline__ void gload16(const void* g, void* l) {
  __builtin_amdgcn_global_load_lds(
      (const __attribute__((address_space(1))) void*)g,
      (__attribute__((address_space(3))) void*)l, 16, 0, 0);
}

__device__ __forceinline__ void hilo(float v, __hip_bfloat16& h, __hip_bfloat16& l) {
  h = __float2bfloat16(v);
  l = __float2bfloat16(v - __bfloat162float(h));
}

// ---------------------------------------------------------------------------
// convx: X fp32 [C,HW] -> Xhi,Xlo bf16 [C,HW] (hi/lo for Gram)
//                         Xt bf16 [HW,C]      (transpose, for the y-GEMM)
// ---------------------------------------------------------------------------
__global__ __launch_bounds__(256) void convx_k(
    const float* __restrict__ x, __hip_bfloat16* __restrict__ xhi,
    __hip_bfloat16* __restrict__ xlo, __hip_bfloat16* __restrict__ xt) {
  const int b = blockIdx.z;
  const int n0 = blockIdx.x * 64, c0 = blockIdx.y * 64;
  const float* xb = x + (long)b * CN;
  __shared__ __hip_bfloat16 t[64][65];
  const int tid = threadIdx.x;
#pragma unroll
  for (int i = 0; i < 16; ++i) {
    int e = i * 256 + tid;
    int r = e >> 6, col = e & 63;
    float v = xb[(long)(c0 + r) * HW + n0 + col];
    __hip_bfloat16 h, l;
    hilo(v, h, l);
    long idx = (long)b * CN + (long)(c0 + r) * HW + n0 + col;
    xhi[idx] = h;
    xlo[idx] = l;
    t[r][col] = h;
  }
  __syncthreads();
#pragma unroll
  for (int i = 0; i < 16; ++i) {
    int e = i * 256 + tid;
    int r = e >> 6, col = e & 63;
    xt[(long)b * CN + (long)(n0 + r) * C + c0 + col] = t[col][r];
  }
}

// ---------------------------------------------------------------------------
// Weight prep: z=0 w_phi->hi/lo; z=1 w_theta->hi/lo; z=2 w_g->transpose bf16;
// z=3 w_mask->bf16.
// ---------------------------------------------------------------------------
__global__ __launch_bounds__(256) void wprep_k(
    const float* __restrict__ wphi, const float* __restrict__ wtheta,
    const float* __restrict__ wg, const float* __restrict__ wmask,
    __hip_bfloat16* __restrict__ wph, __hip_bfloat16* __restrict__ wpl,
    __hip_bfloat16* __restrict__ wth, __hip_bfloat16* __restrict__ wtl,
    __hip_bfloat16* __restrict__ wgT, __hip_bfloat16* __restrict__ wm16) {
  const int z = blockIdx.z;
  const int r0 = blockIdx.y * 64, c0 = blockIdx.x * 64;
  const int tid = threadIdx.x;
  if (z == 2) {
    __shared__ __hip_bfloat16 t[64][65];
#pragma unroll
    for (int i = 0; i < 16; ++i) {
      int e = i * 256 + tid;
      int r = e >> 6, c = e & 63;
      t[r][c] = __float2bfloat16(wg[(long)(r0 + r) * C + c0 + c]);
    }
    __syncthreads();
#pragma unroll
    for (int i = 0; i < 16; ++i) {
      int e = i * 256 + tid;
      int r = e >> 6, c = e & 63;
      wgT[(long)(c0 + r) * C + r0 + c] = t[c][r];
    }
  } else {
#pragma unroll
    for (int i = 0; i < 16; ++i) {
      int e = i * 256 + tid;
      int r = e >> 6, c = e & 63;
      long idx = (long)(r0 + r) * C + c0 + c;
      if (z == 0) {
        __hip_bfloat16 h, l;
        hilo(wphi[idx], h, l);
        wph[idx] = h; wpl[idx] = l;
      } else if (z == 1) {
        __hip_bfloat16 h, l;
        hilo(wtheta[idx], h, l);
        wth[idx] = h; wtl[idx] = l;
      } else {
        wm16[idx] = __float2bfloat16(wmask[idx]);
      }
    }
  }
}

// ---------------------------------------------------------------------------
// Gram = X X^T (symmetric): only lower-triangle 64x64 tiles (36/batch), hi/lo
// MFMA (hh+hl+lh), epilogue writes bf16 hi/lo tile + LDS-transposed mirror.
// ---------------------------------------------------------------------------
__global__ __launch_bounds__(256) void gram_k(
    const __hip_bfloat16* __restrict__ xhi, const __hip_bfloat16* __restrict__ xlo,
    __hip_bfloat16* __restrict__ gh, __hip_bfloat16* __restrict__ gl) {
  const int b = blockIdx.z;
  // triangular decode: tile (i,j) with i <= j
  int i = 0, rem = blockIdx.x;
  while (rem >= 8 - i) { rem -= 8 - i; ++i; }
  const int j = i + rem;
  const int m0 = i * 64, n0 = j * 64;

  const short* Xh = (const short*)(xhi + (long)b * CN);
  const short* Xl = (const short*)(xlo + (long)b * CN);
  __shared__ short lds[4 * 64 * 64];   // 0=Ahi 1=Alo 2=Bhi 3=Blo (32 KB)
  const int tid = threadIdx.x;
  const int w = tid >> 6, lane = tid & 63;

  const short* src = (w & 1) ? Xl : Xh;
  const int rowbase = (w & 2) ? n0 : m0;
  short* ltile = lds + w * 4096;

  f32x4 acc[2][2] = {};
  const int wr = (w >> 1) * 32, wc = (w & 1) * 32;

  for (int k0 = 0; k0 < HW; k0 += 64) {
#pragma unroll
    for (int it = 0; it < 8; ++it) {
      int slot = it * 64 + lane;
      int r = slot >> 3, p = slot & 7, c = p ^ (r & 7);
      gload16(src + (long)(rowbase + r) * HW + k0 + c * 8, ltile + slot * 8);
    }
    __syncthreads();
#pragma unroll
    for (int kh = 0; kh < 2; ++kh) {
      short8 ah[2], al[2], bh[2], bl[2];
      const int ch = kh * 4 + (lane >> 4);
#pragma unroll
      for (int mi = 0; mi < 2; ++mi) {
        int r = wr + mi * 16 + (lane & 15);
        int off = (r * 8 + (ch ^ (r & 7))) * 8;
        ah[mi] = *(const short8*)(lds + off);
        al[mi] = *(const short8*)(lds + 4096 + off);
      }
#pragma unroll
      for (int ni = 0; ni < 2; ++ni) {
        int r = wc + ni * 16 + (lane & 15);
        int off = (r * 8 + (ch ^ (r & 7))) * 8;
        bh[ni] = *(const short8*)(lds + 2 * 4096 + off);
        bl[ni] = *(const short8*)(lds + 3 * 4096 + off);
      }
#pragma unroll
      for (int mi = 0; mi < 2; ++mi)
#pragma unroll
        for (int ni = 0; ni < 2; ++ni) {
          acc[mi][ni] = __builtin_amdgcn_mfma_f32_16x16x32_bf16(ah[mi], bh[ni], acc[mi][ni], 0, 0, 0);
          acc[mi][ni] = __builtin_amdgcn_mfma_f32_16x16x32_bf16(ah[mi], bl[ni], acc[mi][ni], 0, 0, 0);
          acc[mi][ni] = __builtin_amdgcn_mfma_f32_16x16x32_bf16(al[mi], bh[ni], acc[mi][ni], 0, 0, 0);
        }
    }
    __syncthreads();
  }

  // Epilogue: stage fp32 tile in LDS, write direct + mirrored, bf16 hi/lo.
  float* T = (float*)lds;   // [64][65] = 16.6 KB, fits in the 32 KB buffer
#pragma unroll
  for (int mi = 0; mi < 2; ++mi)
#pragma unroll
    for (int ni = 0; ni < 2; ++ni)
#pragma unroll
      for (int rr = 0; rr < 4; ++rr) {
        int rl = wr + mi * 16 + (lane >> 4) * 4 + rr;
        int cl = wc + ni * 16 + (lane & 15);
        T[rl * 65 + cl] = acc[mi][ni][rr];
      }
  __syncthreads();
  __hip_bfloat16* ghb = gh + (long)b * CC;
  __hip_bfloat16* glb = gl + (long)b * CC;
#pragma unroll
  for (int it = 0; it < 16; ++it) {
    int e = it * 256 + tid;
    int r = e >> 6, c = e & 63;
    __hip_bfloat16 h, l;
    hilo(T[r * 65 + c], h, l);
    ghb[(long)(m0 + r) * C + n0 + c] = h;
    glb[(long)(m0 + r) * C + n0 + c] = l;
  }
  if (m0 != n0) {
#pragma unroll
    for (int it = 0; it < 16; ++it) {
      int e = it * 256 + tid;
      int r = e >> 6, c = e & 63;
      __hip_bfloat16 h, l;
      hilo(T[c * 65 + r], h, l);
      ghb[(long)(n0 + r) * C + m0 + c] = h;
      glb[(long)(n0 + r) * C + m0 + c] = l;
    }
  }
}

// ---------------------------------------------------------------------------
// Small NT MFMA GEMM: C[M=512,N=512] = A[512,K=512] * B[512,K]^T, per batch.
// AH/BH: operand has hi/lo split (3 MFMA passes, fp32-grade).
// EPI 0: write hi/lo bf16 (out1,out2); EPI 1: fp32 (out1); EPI 2: bf16 (out1).
// ---------------------------------------------------------------------------
template <int AH, int BH, int EPI>
__global__ __launch_bounds__(256) void nt_small(
    const __hip_bfloat16* __restrict__ Ah_, const __hip_bfloat16* __restrict__ Al_,
    const __hip_bfloat16* __restrict__ Bh_, const __hip_bfloat16* __restrict__ Bl_,
    long aStr, long bStr, void* __restrict__ out1, void* __restrict__ out2) {
  const int b = blockIdx.z;
  const int m0 = blockIdx.y * 64, n0 = blockIdx.x * 64;
  const short* Ahp = (const short*)(Ah_ + (long)b * aStr);
  const short* Alp = AH ? (const short*)(Al_ + (long)b * aStr) : nullptr;
  const short* Bhp = (const short*)(Bh_ + (long)b * bStr);
  const short* Blp = BH ? (const short*)(Bl_ + (long)b * bStr) : nullptr;
  __shared__ short lds[4 * 64 * 64];
  const int tid = threadIdx.x, w = tid >> 6, lane = tid & 63;

  f32x4 acc[2][2] = {};
  const int wr = (w >> 1) * 32, wc = (w & 1) * 32;

  for (int k0 = 0; k0 < 512; k0 += 64) {
    if constexpr (AH && BH) {
      const short* src = (w == 0) ? Ahp : (w == 1) ? Alp : (w == 2) ? Bhp : Blp;
      const int rowbase = (w & 2) ? n0 : m0;
      short* lt = lds + w * 4096;
#pragma unroll
      for (int it = 0; it < 8; ++it) {
        int slot = it * 64 + lane;
        int r = slot >> 3, p = slot & 7, c = p ^ (r & 7);
        gload16(src + (long)(rowbase + r) * 512 + k0 + c * 8, lt + slot * 8);
      }
    } else {
      const short* src = (w < 2) ? Ahp : Bhp;
      const int rowbase = (w < 2) ? m0 : n0;
      short* lt = lds + (w >> 1) * 8192;
#pragma unroll
      for (int it = 0; it < 4; ++it) {
        int slot = (w & 1) * 256 + it * 64 + lane;
        int r = slot >> 3, p = slot & 7, c = p ^ (r & 7);
        gload16(src + (long)(rowbase + r) * 512 + k0 + c * 8, lt + slot * 8);
      }
    }
    __syncthreads();
#pragma unroll
    for (int kh = 0; kh < 2; ++kh) {
      short8 ah[2], al[2], bh[2], bl[2];
      const int ch = kh * 4 + (lane >> 4);
#pragma unroll
      for (int mi = 0; mi < 2; ++mi) {
        int r = wr + mi * 16 + (lane & 15);
        int off = (r * 8 + (ch ^ (r & 7))) * 8;
        ah[mi] = *(const short8*)(lds + off);
        if constexpr (AH) al[mi] = *(const short8*)(lds + 4096 + off);
      }
#pragma unroll
      for (int ni = 0; ni < 2; ++ni) {
        int r = wc + ni * 16 + (lane & 15);
        int off = (r * 8 + (ch ^ (r & 7))) * 8;
        bh[ni] = *(const short8*)(lds + 2 * 4096 + off);
        if constexpr (BH) bl[ni] = *(const short8*)(lds + 3 * 4096 + off);
      }
#pragma unroll
      for (int mi = 0; mi < 2; ++mi)
#pragma unroll
        for (int ni = 0; ni < 2; ++ni) {
          acc[mi][ni] = __builtin_amdgcn_mfma_f32_16x16x32_bf16(ah[mi], bh[ni], acc[mi][ni], 0, 0, 0);
          if constexpr (BH)
            acc[mi][ni] = __builtin_amdgcn_mfma_f32_16x16x32_bf16(ah[mi], bl[ni], acc[mi][ni], 0, 0, 0);
          if constexpr (AH)
            acc[mi][ni] = __builtin_amdgcn_mfma_f32_16x16x32_bf16(al[mi], bh[ni], acc[mi][ni], 0, 0, 0);
        }
    }
    __syncthreads();
  }

#pragma unroll
  for (int mi = 0; mi < 2; ++mi)
#pragma unroll
    for (int ni = 0; ni < 2; ++ni)
#pragma unroll
      for (int rr = 0; rr < 4; ++rr) {
        int row = m0 + wr + mi * 16 + (lane >> 4) * 4 + rr;
        int col = n0 + wc + ni * 16 + (lane & 15);
        long idx = (long)b * CC + (long)row * 512 + col;
        float v = acc[mi][ni][rr];
        if constexpr (EPI == 0) {
          __hip_bfloat16 h, l;
          hilo(v, h, l);
          ((__hip_bfloat16*)out1)[idx] = h;
          ((__hip_bfloat16*)out2)[idx] = l;
        } else if constexpr (EPI == 1) {
          ((float*)out1)[idx] = v;
        } else {
          ((__hip_bfloat16*)out1)[idx] = __float2bfloat16(v);
        }
      }
}

// ---------------------------------------------------------------------------
// Row softmax over 512 cols, fp32 in -> bf16 out.
// ---------------------------------------------------------------------------
__global__ __launch_bounds__(256) void softmax_k(const float* __restrict__ a,
                                                 __hip_bfloat16* __restrict__ o) {
  const float* row = a + (long)blockIdx.x * 512;
  __hip_bfloat16* orow = o + (long)blockIdx.x * 512;
  const int t = threadIdx.x;
  float v0 = row[t], v1 = row[t + 256];
  __shared__ float sm[256];
  sm[t] = fmaxf(v0, v1);
  __syncthreads();
  for (int s = 128; s > 0; s >>= 1) {
    if (t < s) sm[t] = fmaxf(sm[t], sm[t + s]);
    __syncthreads();
  }
  float mx = sm[0];
  __syncthreads();
  float e0 = expf(v0 - mx), e1 = expf(v1 - mx);
  sm[t] = e0 + e1;
  __syncthreads();
  for (int s = 128; s > 0; s >>= 1) {
    if (t < s) sm[t] += sm[t + s];
    __syncthreads();
  }
  float inv = 1.0f / sm[0];
  orow[t] = __float2bfloat16(e0 * inv);
  orow[t + 256] = __float2bfloat16(e1 * inv);
}

// ---------------------------------------------------------------------------
// Big NT MFMA GEMM, 128x128 tile, BK=32, M=512 N=4096 K=512 (unchanged).
// MODE 0: y = Mb (NT) Xt with permuted B-rows -> yvT bf16 (== permute+view).
// MODE 1: out = gamma*(w_mask (NT) yvT) + x, fp32 store.
// ---------------------------------------------------------------------------
template <int MODE>
__global__ __launch_bounds__(256) void big_k(
    const __hip_bfloat16* __restrict__ Aw, const __hip_bfloat16* __restrict__ Bm,
    void* __restrict__ Cout, const float* __restrict__ x,
    const float* __restrict__ gammaPtr, long aStride) {
  const int b = blockIdx.z;
  const int n0 = blockIdx.x * 128, m0 = blockIdx.y * 128;
  const short* A = (const short*)(Aw + (long)b * aStride);
  const short* B = (const short*)(Bm + (long)b * CN);
  __shared__ short lds[2 * 128 * 32];
  const int tid = threadIdx.x, w = tid >> 6, lane = tid & 63;

  f32x4 acc[4][4] = {};
  const int wr = (w >> 1) * 64, wc = (w & 1) * 64;

  for (int k0 = 0; k0 < 512; k0 += 32) {
#pragma unroll
    for (int i = 0; i < 4; ++i) {
      int slot = (w & 1) * 256 + i * 64 + lane;
      int r = slot >> 2, p = slot & 3, c = p ^ ((r >> 1) & 3);
      const short* src;
      long goff;
      if (w < 2) {
        src = A;
        goff = (long)(m0 + r) * 512 + k0 + c * 8;
      } else {
        int gr = (MODE == 0) ? (n0 + (r & 15) * 8 + (r >> 4)) : (n0 + r);
        src = B;
        goff = (long)gr * 512 + k0 + c * 8;
      }
      gload16(src + goff, lds + ((w >> 1) * 512 + slot) * 8);
    }
    __syncthreads();
    short8 af[4], bfr[4];
    const int ch = lane >> 4;
#pragma unroll
    for (int mi = 0; mi < 4; ++mi) {
      int r = wr + mi * 16 + (lane & 15);
      af[mi] = *(const short8*)(lds + (r * 4 + (ch ^ ((r >> 1) & 3))) * 8);
    }
#pragma unroll
    for (int ni = 0; ni < 4; ++ni) {
      int r = wc + ni * 16 + (lane & 15);
      bfr[ni] = *(const short8*)(lds + 4096 + (r * 4 + (ch ^ ((r >> 1) & 3))) * 8);
    }
#pragma unroll
    for (int mi = 0; mi < 4; ++mi)
#pragma unroll
      for (int ni = 0; ni < 4; ++ni)
        acc[mi][ni] = __builtin_amdgcn_mfma_f32_16x16x32_bf16(af[mi], bfr[ni], acc[mi][ni], 0, 0, 0);
    __syncthreads();
  }

  if (MODE == 0) {
    __hip_bfloat16* yv = (__hip_bfloat16*)Cout + (long)b * CN;
    const int u = lane & 15;
#pragma unroll
    for (int mi = 0; mi < 4; ++mi)
#pragma unroll
      for (int ni = 0; ni < 4; ++ni) {
        int t = (wc >> 4) + ni;
        long base = ((long)(t * 512 + m0 + wr + mi * 16 + (lane >> 4) * 4)) * 512 +
                    (n0 >> 3) + u;
#pragma unroll
        for (int r = 0; r < 4; ++r)
          yv[base + (long)r * 512] = __float2bfloat16(acc[mi][ni][r]);
      }
  } else {
    float* outp = (float*)Cout + (long)b * CN;
    const float* xb = x + (long)b * CN;
    const float g0 = gammaPtr[0];
#pragma unroll
    for (int mi = 0; mi < 4; ++mi)
#pragma unroll
      for (int ni = 0; ni < 4; ++ni)
#pragma unroll
        for (int r = 0; r < 4; ++r) {
          long idx = (long)(m0 + wr + mi * 16 + (lane >> 4) * 4 + r) * HW +
                     n0 + wc + ni * 16 + (lane & 15);
          outp[idx] = g0 * acc[mi][ni][r] + xb[idx];
        }
  }
}

// ---------------------------------------------------------------------------
// Orchestration (all-MFMA pipeline). Workspace ~121 MB with aliasing:
//   xhi/xlo/xt: 3x33.6 MB; gh/gl/t1h/t1l: 4x4.2 MB; weights 6x0.5 MB.
//   logits(fp32) aliases gh+gl; attn16=t1h; mb16=t1l; yvT=xhi.
// ---------------------------------------------------------------------------
extern "C" void kernel_launch(void* const* d_in, const int* in_sizes, int n_in,
                              void* d_out, int out_size, void* d_ws, size_t ws_size,
                              hipStream_t stream) {
  const float* x       = (const float*)d_in[0];
  const float* w_phi   = (const float*)d_in[1];
  const float* w_theta = (const float*)d_in[2];
  const float* w_g     = (const float*)d_in[3];
  const float* w_mask  = (const float*)d_in[4];
  const float* gamma   = (const float*)d_in[5];
  float* out = (float*)d_out;

  __hip_bfloat16* xhi = (__hip_bfloat16*)d_ws;
  __hip_bfloat16* xlo = xhi + BATCH * CN;
  __hip_bfloat16* xt  = xlo + BATCH * CN;
  __hip_bfloat16* gh  = xt + BATCH * CN;
  __hip_bfloat16* gl  = gh + BATCH * CC;
  __hip_bfloat16* t1h = gl + BATCH * CC;
  __hip_bfloat16* t1l = t1h + BATCH * CC;
  __hip_bfloat16* wph = t1l + BATCH * CC;
  __hip_bfloat16* wpl = wph + CC;
  __hip_bfloat16* wth = wpl + CC;
  __hip_bfloat16* wtl = wth + CC;
  __hip_bfloat16* wgT = wtl + CC;
  __hip_bfloat16* wm16 = wgT + CC;
  // aliases (stream-ordered lifetimes don't overlap):
  float* logits           = (float*)gh;   // gh+gl dead after step 2
  __hip_bfloat16* attn16  = t1h;          // t1h dead after step 3
  __hip_bfloat16* mb16    = t1l;          // t1l dead after step 3
  __hip_bfloat16* yvT     = xhi;          // xhi/xlo dead after gram

  // 0. conversions
  convx_k<<<dim3(64, 8, BATCH), 256, 0, stream>>>(x, xhi, xlo, xt);
  wprep_k<<<dim3(8, 8, 4), 256, 0, stream>>>(w_phi, w_theta, w_g, w_mask,
                                             wph, wpl, wth, wtl, wgT, wm16);
  // 1. Gram = X X^T (symmetric, hi/lo MFMA) -> bf16 hi/lo
  gram_k<<<dim3(36, 1, BATCH), 256, 0, stream>>>(xhi, xlo, gh, gl);
  // 2. t1 = w_phi @ Gram  (NT vs symmetric gram), hi/lo in+out
  nt_small<1, 1, 0><<<dim3(8, 8, BATCH), 256, 0, stream>>>(
      wph, wpl, gh, gl, 0, CC, t1h, t1l);
  // 3. logits = t1 @ w_theta^T, hi/lo in, fp32 out
  nt_small<1, 1, 1><<<dim3(8, 8, BATCH), 256, 0, stream>>>(
      t1h, t1l, wth, wtl, CC, 0, logits, nullptr);
  // 4. attn = row-softmax(logits) -> bf16
  softmax_k<<<dim3(BATCH * C), dim3(256), 0, stream>>>(logits, attn16);
  // 5. Mb = attn @ w_g = NT(attn, w_g^T), plain bf16
  nt_small<0, 0, 2><<<dim3(8, 8, BATCH), 256, 0, stream>>>(
      attn16, nullptr, wgT, nullptr, CC, 0, mb16, nullptr);
  // 6. y = Mb (NT) Xt -> yvT (permuted store == torch permute+view)
  big_k<0><<<dim3(32, 4, BATCH), 256, 0, stream>>>(mb16, xt, yvT, nullptr, nullptr, CC);
  // 7. out = gamma * (w_mask (NT) yvT) + x
  big_k<1><<<dim3(32, 4, BATCH), 256, 0, stream>>>(wm16, yvT, out, x, gamma, 0);
}